// Round 7
// baseline (103.404 us; speedup 1.0000x reference)
//
#include <hip/hip_runtime.h>
#include <stdint.h>

// NormalizedLoss: batched chamfer + coverage/quality on point clouds.
// x: [32, 2048, 3] fp32, y: [32, 2048, 3] fp32 -> out: [val, cd, cov, qual] fp32.
//
// R7: profile showed the 40us harness ws-poison fill is a fixed floor; nn sits
// ~40us vs a 21us VALU floor with the LDS broadcast pipe + staging stalls as
// the gap. Changes:
//  - q read DIRECTLY from a packed global array via wave-uniform pointers
//    (readfirstlane) -> scalar/broadcast loads, zero LDS in the inner loop,
//    no staging prologue/barrier
//  - -2 folded into p-side regs; pack stores (v0,v1,v2, vn+BIG*invalid)
//  - j-pairs merged with fminf(fminf(...)) -> v_min3_f32 (~4.75 VALU/pair)
//  - per-block outputs (LDS-OR hit partials, direct sums/cnts stores): no
//    global atomics, no memset dispatch. pack + nn + assemble = 3 dispatches.

#define BB 32
#define NP 2048
#define NPTS (BB * NP)  // 65536
#define BIGF 1e10f

typedef unsigned int u32;

// pk[side*NPTS + b*NP + i] = (v0, v1, v2, vn + BIG*invalid)
__global__ __launch_bounds__(256) void pack_kernel(const float* __restrict__ x,
                                                   const float* __restrict__ y,
                                                   float4* __restrict__ pk) {
  int t = blockIdx.x * 256 + threadIdx.x;  // 0 .. 2*NPTS
  int side = t >> 16;
  int i = t & (NPTS - 1);
  const float* src = side ? y : x;
  float v0 = src[3 * i], v1 = src[3 * i + 1], v2 = src[3 * i + 2];
  float vn = v0 * v0 + v1 * v1 + v2 * v2;
  if (v0 + v1 + v2 == 0.0f) vn += BIGF;  // invalid row: out of every min
  pk[t] = make_float4(v0, v1, v2, vn);
}

// embed 11-bit q-index in the mantissa: float order == (d, idx) lexicographic
#define EMB(d, jg) __uint_as_float((__float_as_uint(d) & 0xFFFFF800u) | (u32)(jg))

__global__ __launch_bounds__(512) void nn_kernel(const float4* __restrict__ pk,
                                                 u32* __restrict__ hitpart,
                                                 float* __restrict__ sums_part,
                                                 float* __restrict__ cnts_part) {
  int bid = blockIdx.x;  // 512 blocks: side(2) x b(32) x pc(8)
  int side = bid >> 8;
  int b = (bid >> 3) & 31;
  int pc = bid & 7;
  int tid = threadIdx.x;
  int w = __builtin_amdgcn_readfirstlane(tid >> 6);  // provably wave-uniform
  int lane = tid & 63;

  __shared__ u32 merged[8][256];  // 8KB per-wave embedded (d|idx) partials
  __shared__ float pws[256];      // p.w = pn (+BIG if invalid)
  __shared__ u32 hitlds[64];      // per-block hit bitmask over q indices
  __shared__ float redc[8], redn[8];

  // ---- p fragment: 4 p-points per lane, coalesced float4 loads ----
  const float4* pbase = pk + side * NPTS + b * NP + pc * 256;
  float pmx[4], pmy[4], pmz[4];
  for (int k = 0; k < 4; ++k) {
    float4 p = pbase[lane + 64 * k];
    pmx[k] = -2.0f * p.x; pmy[k] = -2.0f * p.y; pmz[k] = -2.0f * p.z;
    if (w == 0) pws[lane + 64 * k] = p.w;
  }
  if (tid < 64) hitlds[tid] = 0u;

  // ---- inner loop: wave-uniform q stream, pure VALU, no LDS ----
  const float4* qq = pk + (side ^ 1) * NPTS + b * NP + w * 256;
  u32 qoff = (u32)(w * 256);
  float best0 = 3.0e38f, best1 = 3.0e38f, best2 = 3.0e38f, best3 = 3.0e38f;

  // d' = q.w + (-2p).q ; min3 over (best, j, j+1) pairs
#define PROC2(qA, qB, jg)                                                          \
  {                                                                                \
    float a0 = fmaf((qA).x, pmx[0], fmaf((qA).y, pmy[0], fmaf((qA).z, pmz[0], (qA).w))); \
    float a1 = fmaf((qA).x, pmx[1], fmaf((qA).y, pmy[1], fmaf((qA).z, pmz[1], (qA).w))); \
    float a2 = fmaf((qA).x, pmx[2], fmaf((qA).y, pmy[2], fmaf((qA).z, pmz[2], (qA).w))); \
    float a3 = fmaf((qA).x, pmx[3], fmaf((qA).y, pmy[3], fmaf((qA).z, pmz[3], (qA).w))); \
    float b0 = fmaf((qB).x, pmx[0], fmaf((qB).y, pmy[0], fmaf((qB).z, pmz[0], (qB).w))); \
    float b1 = fmaf((qB).x, pmx[1], fmaf((qB).y, pmy[1], fmaf((qB).z, pmz[1], (qB).w))); \
    float b2 = fmaf((qB).x, pmx[2], fmaf((qB).y, pmy[2], fmaf((qB).z, pmz[2], (qB).w))); \
    float b3 = fmaf((qB).x, pmx[3], fmaf((qB).y, pmy[3], fmaf((qB).z, pmz[3], (qB).w))); \
    best0 = fminf(fminf(best0, EMB(a0, jg)), EMB(b0, (jg) + 1));                   \
    best1 = fminf(fminf(best1, EMB(a1, jg)), EMB(b1, (jg) + 1));                   \
    best2 = fminf(fminf(best2, EMB(a2, jg)), EMB(b2, (jg) + 1));                   \
    best3 = fminf(fminf(best3, EMB(a3, jg)), EMB(b3, (jg) + 1));                   \
  }

  // 2-deep rotating pipeline, 8 q per iteration (final prefetch reads 64B past
  // the slice; pk is padded by 64B in ws, loaded-but-unused -> safe)
  float4 qa0 = qq[0], qa1 = qq[1], qa2 = qq[2], qa3 = qq[3];
  for (int jc = 0; jc < 256; jc += 8) {
    float4 qb0 = qq[jc + 4], qb1 = qq[jc + 5], qb2 = qq[jc + 6], qb3 = qq[jc + 7];
    u32 jg = qoff + (u32)jc;
    PROC2(qa0, qa1, jg);
    PROC2(qa2, qa3, jg + 2);
    qa0 = qq[jc + 8]; qa1 = qq[jc + 9]; qa2 = qq[jc + 10]; qa3 = qq[jc + 11];
    PROC2(qb0, qb1, jg + 4);
    PROC2(qb2, qb3, jg + 6);
  }

  merged[w][lane +   0] = __float_as_uint(best0);
  merged[w][lane +  64] = __float_as_uint(best1);
  merged[w][lane + 128] = __float_as_uint(best2);
  merged[w][lane + 192] = __float_as_uint(best3);
  __syncthreads();

  // ---- merge 8 wave-partials; extract (dmin, idx); block-local outputs ----
  float contrib = 0.f, cnt = 0.f;
  if (tid < 256) {
    float bd = __uint_as_float(merged[0][tid]);
#pragma unroll
    for (int ww = 1; ww < 8; ++ww) bd = fminf(bd, __uint_as_float(merged[ww][tid]));
    u32 bits = __float_as_uint(bd);
    u32 bi = bits & 0x7FFu;                            // global q index
    float dmin = __uint_as_float(bits & 0xFFFFF800u);  // truncated min d'
    float pwv = pws[tid];                              // pn (+BIG if invalid p)
    bool valid = (pwv < 1e9f);
    contrib = valid ? (dmin + pwv) : 0.f;              // + ||p||^2, mask invalid
    cnt = valid ? 1.f : 0.f;
    if (valid) atomicOr(&hitlds[bi >> 5], 1u << (bi & 31));
  }
  for (int o = 32; o > 0; o >>= 1) {
    contrib += __shfl_down(contrib, o, 64);
    cnt += __shfl_down(cnt, o, 64);
  }
  if (lane == 0 && w < 4) { redc[w] = contrib; redn[w] = cnt; }
  __syncthreads();
  if (tid == 0) {
    sums_part[bid] = redc[0] + redc[1] + redc[2] + redc[3];
    cnts_part[bid] = redn[0] + redn[1] + redn[2] + redn[3];
  }
  if (tid < 64) hitpart[bid * 64 + tid] = hitlds[tid];
}

// One block, 512 threads: 8 threads per (side,b); OR 8 pc-partials, popcount,
// sum part sums/cnts, then one wave assembles the 4 scalars.
__global__ __launch_bounds__(512) void assemble_kernel(const u32* __restrict__ hitpart,
                                                       const float* __restrict__ sums_part,
                                                       const float* __restrict__ cnts_part,
                                                       float* __restrict__ out) {
  __shared__ float hs[64], ss[64], cs[64];
  int tid = threadIdx.x;
  int sb = tid >> 3, c = tid & 7;  // sb = side*32+b; bid = sb*8 + pc
  float h = 0.f;
  for (int wd = c; wd < 64; wd += 8) {
    u32 m = 0u;
#pragma unroll
    for (int blk = 0; blk < 8; ++blk) m |= hitpart[(sb * 8 + blk) * 64 + wd];
    h += (float)__popc(m);
  }
  h += __shfl_down(h, 4, 8);
  h += __shfl_down(h, 2, 8);
  h += __shfl_down(h, 1, 8);
  if (c == 0) {
    float s = 0.f, n = 0.f;
#pragma unroll
    for (int blk = 0; blk < 8; ++blk) {
      s += sums_part[sb * 8 + blk];
      n += cnts_part[sb * 8 + blk];
    }
    hs[sb] = h; ss[sb] = s; cs[sb] = n;
  }
  __syncthreads();
  if (tid < 64) {
    float cd = 0.f, cov = 0.f, qual = 0.f;
    if (tid < BB) {
      float nx = cs[tid], ny = cs[BB + tid];
      cd = ss[tid] / nx + ss[BB + tid] / ny;
      cov = hs[tid] / ny;        // side0 (p=x) hits y indices: /ny
      qual = hs[BB + tid] / nx;  // side1 (p=y) hits x indices: /nx
    }
    for (int o = 32; o > 0; o >>= 1) {
      cd += __shfl_down(cd, o, 64);
      cov += __shfl_down(cov, o, 64);
      qual += __shfl_down(qual, o, 64);
    }
    if (tid == 0) {
      cd /= (float)BB; cov /= (float)BB; qual /= (float)BB;
      out[0] = cd - 1e-4f * cov - 1e-4f * qual;  // WCD*cd - WCOV*cov - WQUAL*qual
      out[1] = cd;
      out[2] = cov;
      out[3] = qual;
    }
  }
}

extern "C" void kernel_launch(void* const* d_in, const int* in_sizes, int n_in,
                              void* d_out, int out_size, void* d_ws, size_t ws_size,
                              hipStream_t stream) {
  const float* x = (const float*)d_in[0];
  const float* y = (const float*)d_in[1];
  float* out = (float*)d_out;
  char* ws = (char*)d_ws;

  // ws layout (all regions fully written by producers before consumers read;
  // no memset needed despite 0xAA poison):
  //   [0, 131072)        hitpart: 512 blocks x 64 u32
  //   [131072, +2048)    sums_part: 512 f32
  //   [133120, +2048)    cnts_part: 512 f32
  //   [135168, +2MB+64)  pk: 2*NPTS float4 (+64B prefetch pad)
  u32* hitpart = (u32*)ws;
  float* sums_part = (float*)(ws + 131072);
  float* cnts_part = (float*)(ws + 133120);
  float4* pk = (float4*)(ws + 135168);

  pack_kernel<<<2 * NPTS / 256, 256, 0, stream>>>(x, y, pk);
  nn_kernel<<<2 * BB * 8, 512, 0, stream>>>(pk, hitpart, sums_part, cnts_part);
  assemble_kernel<<<1, 512, 0, stream>>>(hitpart, sums_part, cnts_part, out);
}

// Round 8
// 95.261 us; speedup vs baseline: 1.0855x; 1.0855x over previous
//
#include <hip/hip_runtime.h>
#include <stdint.h>

// NormalizedLoss: batched chamfer + coverage/quality on point clouds.
// x: [32, 2048, 3] fp32, y: [32, 2048, 3] fp32 -> out: [val, cd, cov, qual] fp32.
//
// R8: R7 showed VGPR pinned at 28 by the backend's occupancy heuristic ->
// pipeline spilled, ~2x dynamic VALU. Changes:
//  - v_pk_fma_f32 (VOP3P packed fp32, inline asm) with q packed in PAIRS:
//    split global arrays qsX/Y/Z/W of float2 (x_j,x_j+1)... so loads land
//    directly in packed operands; -2p dup'd into loop-invariant pairs.
//    3.0 VALU/pair (12 pk_fma + 8 v_and_or + 4 v_min3 per q-pair x 8p).
//  - P=8, 1024-thread blocks (16 waves, 4/SIMD), grid 256 = 1 block/CU.
//    q streamed from global (wave-uniform addr -> TCP broadcast, L2-resident).
//  - amdgpu_waves_per_eu(4,4): pin register budget at 128, stop the shrink.

#define BB 32
#define NP 2048
#define BIGF 1e10f

typedef unsigned int u32;
typedef float f2 __attribute__((ext_vector_type(2)));

// embed 11-bit q-index in the mantissa: float order == (d, idx) lexicographic
#define EMB(d, jg) __uint_as_float((__float_as_uint(d) & 0xFFFFF800u) | (u32)(jg))

__device__ __forceinline__ f2 pk_fma(f2 a, f2 b, f2 c) {
  f2 d;
  asm("v_pk_fma_f32 %0, %1, %2, %3" : "=v"(d) : "v"(a), "v"(b), "v"(c));
  return d;
}

// Pack q into pair-split arrays: record t covers points (2t, 2t+1) of its side.
// qsX[t]=(x0,x1) qsY[t]=(y0,y1) qsZ[t]=(z0,z1) qsW[t]=(n0[+BIG], n1[+BIG])
__global__ __launch_bounds__(256) void pack2_kernel(const float* __restrict__ x,
                                                    const float* __restrict__ y,
                                                    f2* __restrict__ qsX, f2* __restrict__ qsY,
                                                    f2* __restrict__ qsZ, f2* __restrict__ qsW) {
  int t = blockIdx.x * 256 + threadIdx.x;  // 0..65535 pair records
  int side = t >> 15;                      // 32768 records per side
  int i = t & 32767;
  const float* src = (side ? y : x) + 6 * i;
  float a0 = src[0], a1 = src[1], a2 = src[2];  // point 2i
  float b0 = src[3], b1 = src[4], b2 = src[5];  // point 2i+1
  float na = a0 * a0 + a1 * a1 + a2 * a2;
  float nb = b0 * b0 + b1 * b1 + b2 * b2;
  if (a0 + a1 + a2 == 0.0f) na += BIGF;  // invalid row: out of every min
  if (b0 + b1 + b2 == 0.0f) nb += BIGF;
  qsX[t] = (f2){a0, b0};
  qsY[t] = (f2){a1, b1};
  qsZ[t] = (f2){a2, b2};
  qsW[t] = (f2){na, nb};
}

__device__ __forceinline__ void procrec(f2 qx2, f2 qy2, f2 qz2, f2 qw2, u32 jg,
                                        const f2* pmx, const f2* pmy, const f2* pmz,
                                        float* best) {
#pragma unroll
  for (int k = 0; k < 8; ++k) {
    f2 d2 = pk_fma(qx2, pmx[k], pk_fma(qy2, pmy[k], pk_fma(qz2, pmz[k], qw2)));
    best[k] = fminf(fminf(best[k], EMB(d2.x, jg)), EMB(d2.y, jg + 1));
  }
}

__global__ __launch_bounds__(1024) __attribute__((amdgpu_waves_per_eu(4, 4)))
void nn_kernel(const f2* __restrict__ qsX, const f2* __restrict__ qsY,
               const f2* __restrict__ qsZ, const f2* __restrict__ qsW,
               u32* __restrict__ hitpart, float* __restrict__ sums_part,
               float* __restrict__ cnts_part) {
  int bid = blockIdx.x;  // 256 blocks: side(1)|b(5)|pc(2); block = 512 p x 2048 q
  int side = bid >> 7;
  int b = (bid >> 2) & 31;
  int pc = bid & 3;
  int tid = threadIdx.x;
  int w = __builtin_amdgcn_readfirstlane(tid >> 6);  // 0..15, wave-uniform
  int lane = tid & 63;

  __shared__ u32 merged[16][512];  // 32KB: per-wave embedded (d|idx) partials
  __shared__ float pws[512];       // pn (+BIG if invalid) per local p
  __shared__ u32 hitlds[64];       // block-local hit bitmask over 2048 q
  __shared__ float redc[8], redn[8];

  // ---- p prologue: 4 pair-records/lane = 8 p; dup -2p into packed pairs ----
  int prec0 = side * 32768 + b * 1024 + pc * 256;
  f2 pmx[8], pmy[8], pmz[8];
  float best[8];
#pragma unroll
  for (int k = 0; k < 4; ++k) {
    int rec = prec0 + lane + 64 * k;
    f2 px = qsX[rec], py = qsY[rec], pz = qsZ[rec], pw = qsW[rec];
    pmx[2 * k] = (f2){-2.f * px.x, -2.f * px.x};
    pmx[2 * k + 1] = (f2){-2.f * px.y, -2.f * px.y};
    pmy[2 * k] = (f2){-2.f * py.x, -2.f * py.x};
    pmy[2 * k + 1] = (f2){-2.f * py.y, -2.f * py.y};
    pmz[2 * k] = (f2){-2.f * pz.x, -2.f * pz.x};
    pmz[2 * k + 1] = (f2){-2.f * pz.y, -2.f * pz.y};
    if (w == 0) ((f2*)pws)[lane + 64 * k] = pw;  // pws[2(lane+64k)+{0,1}]
  }
#pragma unroll
  for (int k = 0; k < 8; ++k) best[k] = 3.0e38f;
  if (tid < 64) hitlds[tid] = 0u;

  // ---- inner loop: wave's 64 q-pair records, 2-deep rotating prefetch ----
  int qrec0 = (side ^ 1) * 32768 + b * 1024 + w * 64;
  const f2* qX = qsX + qrec0;
  const f2* qY = qsY + qrec0;
  const f2* qZ = qsZ + qrec0;
  const f2* qW = qsW + qrec0;
  u32 j0 = (u32)(w * 128);  // global q index of record 0

  f2 x0 = qX[0], y0 = qY[0], z0 = qZ[0], w0 = qW[0];
  f2 x1 = qX[1], y1 = qY[1], z1 = qZ[1], w1 = qW[1];
  for (int r = 0; r < 64; r += 2) {
    // prefetch next group (final iter reads 2 records past end: arrays padded)
    f2 x2 = qX[r + 2], y2 = qY[r + 2], z2 = qZ[r + 2], w2 = qW[r + 2];
    f2 x3 = qX[r + 3], y3 = qY[r + 3], z3 = qZ[r + 3], w3 = qW[r + 3];
    procrec(x0, y0, z0, w0, j0 + 2 * r, pmx, pmy, pmz, best);
    procrec(x1, y1, z1, w1, j0 + 2 * r + 2, pmx, pmy, pmz, best);
    x0 = x2; y0 = y2; z0 = z2; w0 = w2;
    x1 = x3; y1 = y3; z1 = z3; w1 = w3;
  }

  // ---- write wave partials (pairs -> ds_write_b64) ----
#pragma unroll
  for (int k = 0; k < 4; ++k) {
    uint2 v = make_uint2(__float_as_uint(best[2 * k]), __float_as_uint(best[2 * k + 1]));
    *(uint2*)&merged[w][2 * (lane + 64 * k)] = v;
  }
  __syncthreads();

  // ---- merge 16 wave partials per p; extract; block-local outputs ----
  float contrib = 0.f, cnt = 0.f;
  if (tid < 512) {
    float bd = __uint_as_float(merged[0][tid]);
#pragma unroll
    for (int ww = 1; ww < 16; ++ww) bd = fminf(bd, __uint_as_float(merged[ww][tid]));
    u32 bits = __float_as_uint(bd);
    u32 bi = bits & 0x7FFu;                            // global q index
    float dmin = __uint_as_float(bits & 0xFFFFF800u);  // truncated min d'
    float pwv = pws[tid];                              // pn (+BIG if invalid p)
    bool valid = (pwv < 1e9f);
    contrib = valid ? (dmin + pwv) : 0.f;              // + ||p||^2, mask invalid
    cnt = valid ? 1.f : 0.f;
    if (valid) atomicOr(&hitlds[bi >> 5], 1u << (bi & 31));
  }
  for (int o = 32; o > 0; o >>= 1) {
    contrib += __shfl_down(contrib, o, 64);
    cnt += __shfl_down(cnt, o, 64);
  }
  if (tid < 512 && lane == 0) { redc[tid >> 6] = contrib; redn[tid >> 6] = cnt; }
  __syncthreads();
  if (tid == 0) {
    float s = 0.f, n = 0.f;
#pragma unroll
    for (int i = 0; i < 8; ++i) { s += redc[i]; n += redn[i]; }
    sums_part[bid] = s;
    cnts_part[bid] = n;
  }
  if (tid < 64) hitpart[bid * 64 + tid] = hitlds[tid];
}

// One block, 512 threads: 8 threads per (side,b); OR 4 pc-partials, popcount,
// sum part sums/cnts, then one wave assembles the 4 scalars.
__global__ __launch_bounds__(512) void assemble_kernel(const u32* __restrict__ hitpart,
                                                       const float* __restrict__ sums_part,
                                                       const float* __restrict__ cnts_part,
                                                       float* __restrict__ out) {
  __shared__ float hs[64], ss[64], cs[64];
  int tid = threadIdx.x;
  int sb = tid >> 3, c = tid & 7;  // sb = side*32+b; part bid = sb*4 + pc
  float h = 0.f;
  for (int wd = c; wd < 64; wd += 8) {
    u32 m = 0u;
#pragma unroll
    for (int blk = 0; blk < 4; ++blk) m |= hitpart[(sb * 4 + blk) * 64 + wd];
    h += (float)__popc(m);
  }
  h += __shfl_down(h, 4, 8);
  h += __shfl_down(h, 2, 8);
  h += __shfl_down(h, 1, 8);
  if (c == 0) {
    float s = 0.f, n = 0.f;
#pragma unroll
    for (int blk = 0; blk < 4; ++blk) {
      s += sums_part[sb * 4 + blk];
      n += cnts_part[sb * 4 + blk];
    }
    hs[sb] = h; ss[sb] = s; cs[sb] = n;
  }
  __syncthreads();
  if (tid < 64) {
    float cd = 0.f, cov = 0.f, qual = 0.f;
    if (tid < BB) {
      float nx = cs[tid], ny = cs[BB + tid];
      cd = ss[tid] / nx + ss[BB + tid] / ny;
      cov = hs[tid] / ny;        // side0 (p=x) hits y indices: /ny
      qual = hs[BB + tid] / nx;  // side1 (p=y) hits x indices: /nx
    }
    for (int o = 32; o > 0; o >>= 1) {
      cd += __shfl_down(cd, o, 64);
      cov += __shfl_down(cov, o, 64);
      qual += __shfl_down(qual, o, 64);
    }
    if (tid == 0) {
      cd /= (float)BB; cov /= (float)BB; qual /= (float)BB;
      out[0] = cd - 1e-4f * cov - 1e-4f * qual;  // WCD*cd - WCOV*cov - WQUAL*qual
      out[1] = cd;
      out[2] = cov;
      out[3] = qual;
    }
  }
}

extern "C" void kernel_launch(void* const* d_in, const int* in_sizes, int n_in,
                              void* d_out, int out_size, void* d_ws, size_t ws_size,
                              hipStream_t stream) {
  const float* x = (const float*)d_in[0];
  const float* y = (const float*)d_in[1];
  float* out = (float*)d_out;
  char* ws = (char*)d_ws;

  // ws layout (all regions fully written by producers; no memset needed):
  //   [0, 64KB)       hitpart: 256 part-blocks x 64 u32
  //   [64KB, +1KB)    sums_part: 256 f32
  //   [65KB, +1KB)    cnts_part: 256 f32
  //   [66KB ...)      qsX/qsY/qsZ/qsW: (65536+2) f2 each (+2-record prefetch pad)
  const size_t QSZ = (65536 + 8) * sizeof(f2);  // 8-record pad, 16B-align friendly
  u32* hitpart = (u32*)ws;
  float* sums_part = (float*)(ws + 65536);
  float* cnts_part = (float*)(ws + 66560);
  f2* qsX = (f2*)(ws + 67584);
  f2* qsY = (f2*)(ws + 67584 + QSZ);
  f2* qsZ = (f2*)(ws + 67584 + 2 * QSZ);
  f2* qsW = (f2*)(ws + 67584 + 3 * QSZ);

  pack2_kernel<<<256, 256, 0, stream>>>(x, y, qsX, qsY, qsZ, qsW);
  nn_kernel<<<256, 1024, 0, stream>>>(qsX, qsY, qsZ, qsW, hitpart, sums_part, cnts_part);
  assemble_kernel<<<1, 512, 0, stream>>>(hitpart, sums_part, cnts_part, out);
}

// Round 9
// 92.772 us; speedup vs baseline: 1.1146x; 1.0268x over previous
//
#include <hip/hip_runtime.h>
#include <stdint.h>

// NormalizedLoss: batched chamfer + coverage/quality on point clouds.
// x: [32, 2048, 3] fp32, y: [32, 2048, 3] fp32 -> out: [val, cd, cov, qual] fp32.
//
// R9: consolidation. R5-R8 showed three nn structures all at 38-50us
// (~50-65% issue efficiency); R8's asm pk_fma forced register-pair shuffling
// and kept a pack dispatch. This round:
//  - R6's proven shape: 512 blocks x 512 thr, P=4, 8-wave q-split, LDS q.
//  - q staged as PAIR records (x0,x1,y0,y1)(z0,z1,n0,n1): ds_read_b128 lands
//    packed f2 operands in adjacent regs; inner loop in f2 vector arithmetic
//    (fp contract fast) -> compiler emits v_pk_fma_f32 (3.0 VALU/pair floor
//    10.2us) or scalar falls back to 4.5/pair. No inline asm.
//  - amdgpu_waves_per_eu(4,4): pin register budget (stop the VGPR-28 shrink).
//  - staging fused in prologue (no pack kernel); block-local outputs (no
//    memset). 2 dispatches: nn + assemble. Fixed floor: 41us harness ws-fill.

#define BB 32
#define NP 2048
#define BIGF 1e10f

typedef unsigned int u32;
typedef float f2 __attribute__((ext_vector_type(2)));

// embed 11-bit q-index in the mantissa: float order == (d, idx) lexicographic
#define EMB(d, jg) __uint_as_float((__float_as_uint(d) & 0xFFFFF800u) | (u32)(jg))

__global__ __launch_bounds__(512) __attribute__((amdgpu_waves_per_eu(4, 4)))
void nn_fused_kernel(const float* __restrict__ x, const float* __restrict__ y,
                     u32* __restrict__ hitpart, float* __restrict__ sums_part,
                     float* __restrict__ cnts_part) {
#pragma clang fp contract(fast)
  int bid = blockIdx.x;  // 512 blocks: side(1)|b(5)|pc(3); block = 256 p x 2048 q
  int side = bid >> 8;
  int b = (bid >> 3) & 31;
  int pc = bid & 7;
  int tid = threadIdx.x;
  int w = __builtin_amdgcn_readfirstlane(tid >> 6);  // 0..7, wave-uniform
  int lane = tid & 63;

  __shared__ float4 qs[2048];     // 32KB; record r -> qs[2r]=(x0,x1,y0,y1), qs[2r+1]=(z0,z1,n0,n1)
  __shared__ u32 merged[8][256];  // 8KB per-wave embedded (d|idx) partials
  __shared__ float pws[256];      // pn (+BIG if invalid) per local p
  __shared__ u32 hitlds[64];      // block-local hit bitmask over 2048 q
  __shared__ float redc[4], redn[4];

  // ---- stage 1024 pair-records (2048 q) of this (side,b); 2 records/thread ----
  {
    const float* qraw = (side ? x : y) + b * NP * 3 + tid * 12;  // 4 points
    float4 f0 = *(const float4*)(qraw);
    float4 f1 = *(const float4*)(qraw + 4);
    float4 g2 = *(const float4*)(qraw + 8);
    // P0=(f0.x,f0.y,f0.z) P1=(f0.w,f1.x,f1.y) P2=(f1.z,f1.w,g2.x) P3=(g2.y,g2.z,g2.w)
    float n0 = f0.x * f0.x + f0.y * f0.y + f0.z * f0.z;
    float n1 = f0.w * f0.w + f1.x * f1.x + f1.y * f1.y;
    float n2 = f1.z * f1.z + f1.w * f1.w + g2.x * g2.x;
    float n3 = g2.y * g2.y + g2.z * g2.z + g2.w * g2.w;
    if (f0.x + f0.y + f0.z == 0.f) n0 += BIGF;  // invalid rows out of every min
    if (f0.w + f1.x + f1.y == 0.f) n1 += BIGF;
    if (f1.z + f1.w + g2.x == 0.f) n2 += BIGF;
    if (g2.y + g2.z + g2.w == 0.f) n3 += BIGF;
    qs[4 * tid + 0] = make_float4(f0.x, f0.w, f0.y, f1.x);  // x0,x1,y0,y1
    qs[4 * tid + 1] = make_float4(f0.z, f1.y, n0, n1);      // z0,z1,n0,n1
    qs[4 * tid + 2] = make_float4(f1.z, g2.y, f1.w, g2.z);
    qs[4 * tid + 3] = make_float4(g2.x, g2.w, n2, n3);
  }

  // ---- p prologue: every wave loads the SAME 256 p; -2p dup'd into f2 ----
  const float* praw = (side ? y : x) + (b * NP + pc * 256) * 3;
  f2 pmx[4], pmy[4], pmz[4];
  float best[4];
#pragma unroll
  for (int k = 0; k < 4; ++k) {
    int pl = lane + 64 * k;
    float p0 = praw[3 * pl], p1 = praw[3 * pl + 1], p2 = praw[3 * pl + 2];
    pmx[k] = (f2){-2.f * p0, -2.f * p0};
    pmy[k] = (f2){-2.f * p1, -2.f * p1};
    pmz[k] = (f2){-2.f * p2, -2.f * p2};
    if (w == 0) {
      float pn = p0 * p0 + p1 * p1 + p2 * p2;
      if (p0 + p1 + p2 == 0.f) pn += BIGF;
      pws[pl] = pn;
    }
    best[k] = 3.0e38f;
  }
  if (tid < 64) hitlds[tid] = 0u;
  __syncthreads();

  // ---- inner loop: wave's 128 records (256 q) vs its 4 p-points ----
  const float4* qr = &qs[w * 256];  // record r of this wave: qr[2r], qr[2r+1]
  u32 j0 = (u32)(w * 256);          // global q index of this wave's record 0
#pragma unroll 4
  for (int r = 0; r < 128; ++r) {
    float4 A = qr[2 * r];      // wave-uniform ds_read_b128 (broadcast)
    float4 B = qr[2 * r + 1];
    f2 qx2 = (f2){A.x, A.y};   // adjacent regs of the b128 -> free pairing
    f2 qy2 = (f2){A.z, A.w};
    f2 qz2 = (f2){B.x, B.y};
    f2 qw2 = (f2){B.z, B.w};
    u32 jg = j0 + 2 * (u32)r;
#pragma unroll
    for (int k = 0; k < 4; ++k) {
      f2 d2 = qx2 * pmx[k] + (qy2 * pmy[k] + (qz2 * pmz[k] + qw2));  // 3 pk_fma
      best[k] = fminf(fminf(best[k], EMB(d2.x, jg)), EMB(d2.y, jg + 1));  // and_or x2 + min3
    }
  }

  merged[w][lane +   0] = __float_as_uint(best[0]);
  merged[w][lane +  64] = __float_as_uint(best[1]);
  merged[w][lane + 128] = __float_as_uint(best[2]);
  merged[w][lane + 192] = __float_as_uint(best[3]);
  __syncthreads();

  // ---- merge 8 wave partials; extract (dmin, idx); block-local outputs ----
  float contrib = 0.f, cnt = 0.f;
  if (tid < 256) {
    float bd = __uint_as_float(merged[0][tid]);
#pragma unroll
    for (int ww = 1; ww < 8; ++ww) bd = fminf(bd, __uint_as_float(merged[ww][tid]));
    u32 bits = __float_as_uint(bd);
    u32 bi = bits & 0x7FFu;                            // global q index
    float dmin = __uint_as_float(bits & 0xFFFFF800u);  // truncated min d'
    float pwv = pws[tid];                              // pn (+BIG if invalid p)
    bool valid = (pwv < 1e9f);
    contrib = valid ? (dmin + pwv) : 0.f;              // + ||p||^2, mask invalid
    cnt = valid ? 1.f : 0.f;
    if (valid) atomicOr(&hitlds[bi >> 5], 1u << (bi & 31));
  }
  for (int o = 32; o > 0; o >>= 1) {
    contrib += __shfl_down(contrib, o, 64);
    cnt += __shfl_down(cnt, o, 64);
  }
  if (tid < 256 && lane == 0) { redc[w] = contrib; redn[w] = cnt; }
  __syncthreads();
  if (tid == 0) {
    sums_part[bid] = redc[0] + redc[1] + redc[2] + redc[3];
    cnts_part[bid] = redn[0] + redn[1] + redn[2] + redn[3];
  }
  if (tid < 64) hitpart[bid * 64 + tid] = hitlds[tid];
}

// One block, 512 threads: 8 threads per (side,b); OR 8 pc-partials, popcount,
// sum part sums/cnts, then one wave assembles the 4 scalars.
__global__ __launch_bounds__(512) void assemble_kernel(const u32* __restrict__ hitpart,
                                                       const float* __restrict__ sums_part,
                                                       const float* __restrict__ cnts_part,
                                                       float* __restrict__ out) {
  __shared__ float hs[64], ss[64], cs[64];
  int tid = threadIdx.x;
  int sb = tid >> 3, c = tid & 7;  // sb = side*32+b; part bid = sb*8 + pc
  float h = 0.f;
  for (int wd = c; wd < 64; wd += 8) {
    u32 m = 0u;
#pragma unroll
    for (int blk = 0; blk < 8; ++blk) m |= hitpart[(sb * 8 + blk) * 64 + wd];
    h += (float)__popc(m);
  }
  h += __shfl_down(h, 4, 8);
  h += __shfl_down(h, 2, 8);
  h += __shfl_down(h, 1, 8);
  if (c == 0) {
    float s = 0.f, n = 0.f;
#pragma unroll
    for (int blk = 0; blk < 8; ++blk) {
      s += sums_part[sb * 8 + blk];
      n += cnts_part[sb * 8 + blk];
    }
    hs[sb] = h; ss[sb] = s; cs[sb] = n;
  }
  __syncthreads();
  if (tid < 64) {
    float cd = 0.f, cov = 0.f, qual = 0.f;
    if (tid < BB) {
      float nx = cs[tid], ny = cs[BB + tid];
      cd = ss[tid] / nx + ss[BB + tid] / ny;
      cov = hs[tid] / ny;        // side0 (p=x) hits y indices: /ny
      qual = hs[BB + tid] / nx;  // side1 (p=y) hits x indices: /nx
    }
    for (int o = 32; o > 0; o >>= 1) {
      cd += __shfl_down(cd, o, 64);
      cov += __shfl_down(cov, o, 64);
      qual += __shfl_down(qual, o, 64);
    }
    if (tid == 0) {
      cd /= (float)BB; cov /= (float)BB; qual /= (float)BB;
      out[0] = cd - 1e-4f * cov - 1e-4f * qual;  // WCD*cd - WCOV*cov - WQUAL*qual
      out[1] = cd;
      out[2] = cov;
      out[3] = qual;
    }
  }
}

extern "C" void kernel_launch(void* const* d_in, const int* in_sizes, int n_in,
                              void* d_out, int out_size, void* d_ws, size_t ws_size,
                              hipStream_t stream) {
  const float* x = (const float*)d_in[0];
  const float* y = (const float*)d_in[1];
  float* out = (float*)d_out;
  char* ws = (char*)d_ws;

  // ws layout (all regions fully written by producers; no memset needed):
  //   [0, 128KB)      hitpart: 512 blocks x 64 u32
  //   [128KB, +2KB)   sums_part: 512 f32
  //   [130KB, +2KB)   cnts_part: 512 f32
  u32* hitpart = (u32*)ws;
  float* sums_part = (float*)(ws + 131072);
  float* cnts_part = (float*)(ws + 133120);

  nn_fused_kernel<<<512, 512, 0, stream>>>(x, y, hitpart, sums_part, cnts_part);
  assemble_kernel<<<1, 512, 0, stream>>>(hitpart, sums_part, cnts_part, out);
}

// Round 10
// 92.307 us; speedup vs baseline: 1.1202x; 1.0050x over previous
//
#include <hip/hip_runtime.h>
#include <stdint.h>

// NormalizedLoss: batched chamfer + coverage/quality on point clouds.
// x: [32, 2048, 3] fp32, y: [32, 2048, 3] fp32 -> out: [val, cd, cov, qual] fp32.
//
// R10: R9 == R6 == ~40us with VALU-busy 25us -> the f2 ext-vector source did
// NOT form v_pk_fma_f32 (scalar static ~18-20us matches the 1.25x busy ratio;
// packed static ~13us would not). This round forces the packed path in asm,
// on R9's unchanged structure (512blk x 512thr, P=4, 8-wave q-split, LDS
// pair-records, block-local outputs, 2 dispatches):
//   per record (2q x 4p = 8 cells): 4 x (3 v_pk_fma_f32 + 2 v_and_or_b32 +
//   1 v_min3_f32) + 2 ds_read_b128 + 2 v_add = ~3.2 VALU/cell = ~11us static
//   (vs ~18-20 scalar). ds_read_b128 lands pairs in aligned adjacent regs ->
//   no repacking moves (unlike R8's 4-array split streams).

#define BB 32
#define NP 2048
#define BIGF 1e10f

typedef unsigned int u32;
typedef float f2 __attribute__((ext_vector_type(2)));

// embed 11-bit q-index in the mantissa: float order == (d, idx) lexicographic
#define EMB(d, jg) __uint_as_float((__float_as_uint(d) & 0xFFFFF800u) | (jg))

__device__ __forceinline__ f2 pk_fma(f2 a, f2 b, f2 c) {
  f2 d;
  asm("v_pk_fma_f32 %0, %1, %2, %3" : "=v"(d) : "v"(a), "v"(b), "v"(c));
  return d;
}
__device__ __forceinline__ float min3(float a, float b, float c) {
  float r;
  asm("v_min3_f32 %0, %1, %2, %3" : "=v"(r) : "v"(a), "v"(b), "v"(c));
  return r;
}

__global__ __launch_bounds__(512) __attribute__((amdgpu_waves_per_eu(4, 4)))
void nn_fused_kernel(const float* __restrict__ x, const float* __restrict__ y,
                     u32* __restrict__ hitpart, float* __restrict__ sums_part,
                     float* __restrict__ cnts_part) {
  int bid = blockIdx.x;  // 512 blocks: side(1)|b(5)|pc(3); block = 256 p x 2048 q
  int side = bid >> 8;
  int b = (bid >> 3) & 31;
  int pc = bid & 7;
  int tid = threadIdx.x;
  int w = __builtin_amdgcn_readfirstlane(tid >> 6);  // 0..7, wave-uniform
  int lane = tid & 63;

  __shared__ float4 qs[2048];     // 32KB; record r -> qs[2r]=(x0,x1,y0,y1), qs[2r+1]=(z0,z1,n0,n1)
  __shared__ u32 merged[8][256];  // 8KB per-wave embedded (d|idx) partials
  __shared__ float pws[256];      // pn (+BIG if invalid) per local p
  __shared__ u32 hitlds[64];      // block-local hit bitmask over 2048 q
  __shared__ float redc[4], redn[4];

  // ---- stage 1024 pair-records (2048 q) of this (side,b); 2 records/thread ----
  {
    const float* qraw = (side ? x : y) + b * NP * 3 + tid * 12;  // 4 points
    float4 f0 = *(const float4*)(qraw);
    float4 f1 = *(const float4*)(qraw + 4);
    float4 g2 = *(const float4*)(qraw + 8);
    // P0=(f0.x,f0.y,f0.z) P1=(f0.w,f1.x,f1.y) P2=(f1.z,f1.w,g2.x) P3=(g2.y,g2.z,g2.w)
    float n0 = f0.x * f0.x + f0.y * f0.y + f0.z * f0.z;
    float n1 = f0.w * f0.w + f1.x * f1.x + f1.y * f1.y;
    float n2 = f1.z * f1.z + f1.w * f1.w + g2.x * g2.x;
    float n3 = g2.y * g2.y + g2.z * g2.z + g2.w * g2.w;
    if (f0.x + f0.y + f0.z == 0.f) n0 += BIGF;  // invalid rows out of every min
    if (f0.w + f1.x + f1.y == 0.f) n1 += BIGF;
    if (f1.z + f1.w + g2.x == 0.f) n2 += BIGF;
    if (g2.y + g2.z + g2.w == 0.f) n3 += BIGF;
    qs[4 * tid + 0] = make_float4(f0.x, f0.w, f0.y, f1.x);  // x0,x1,y0,y1
    qs[4 * tid + 1] = make_float4(f0.z, f1.y, n0, n1);      // z0,z1,n0,n1
    qs[4 * tid + 2] = make_float4(f1.z, g2.y, f1.w, g2.z);
    qs[4 * tid + 3] = make_float4(g2.x, g2.w, n2, n3);
  }

  // ---- p prologue: every wave loads the SAME 256 p; -2p dup'd into f2 ----
  const float* praw = (side ? y : x) + (b * NP + pc * 256) * 3;
  f2 pmx[4], pmy[4], pmz[4];
  float best[4];
#pragma unroll
  for (int k = 0; k < 4; ++k) {
    int pl = lane + 64 * k;
    float p0 = praw[3 * pl], p1 = praw[3 * pl + 1], p2 = praw[3 * pl + 2];
    pmx[k] = (f2){-2.f * p0, -2.f * p0};
    pmy[k] = (f2){-2.f * p1, -2.f * p1};
    pmz[k] = (f2){-2.f * p2, -2.f * p2};
    if (w == 0) {
      float pn = p0 * p0 + p1 * p1 + p2 * p2;
      if (p0 + p1 + p2 == 0.f) pn += BIGF;
      pws[pl] = pn;
    }
    best[k] = 3.0e38f;
  }
  if (tid < 64) hitlds[tid] = 0u;
  __syncthreads();

  // ---- inner loop: wave's 128 records (256 q) vs its 4 p-points ----
  const float4* qr = &qs[w * 256];  // record r of this wave: qr[2r], qr[2r+1]
  u32 je = (u32)(w * 256);          // even global q index of record 0
#pragma unroll 8
  for (int r = 0; r < 128; ++r) {
    float4 A = qr[2 * r];      // wave-uniform ds_read_b128 (broadcast)
    float4 B = qr[2 * r + 1];
    f2 qx2 = (f2){A.x, A.y};   // adjacent regs of the b128 -> free pairing
    f2 qy2 = (f2){A.z, A.w};
    f2 qz2 = (f2){B.x, B.y};
    f2 qw2 = (f2){B.z, B.w};
    u32 jg = je + 2 * (u32)r, jg1 = jg + 1;
#pragma unroll
    for (int k = 0; k < 4; ++k) {
      f2 d2 = pk_fma(qx2, pmx[k], pk_fma(qy2, pmy[k], pk_fma(qz2, pmz[k], qw2)));
      best[k] = min3(best[k], EMB(d2.x, jg), EMB(d2.y, jg1));
    }
  }

  merged[w][lane +   0] = __float_as_uint(best[0]);
  merged[w][lane +  64] = __float_as_uint(best[1]);
  merged[w][lane + 128] = __float_as_uint(best[2]);
  merged[w][lane + 192] = __float_as_uint(best[3]);
  __syncthreads();

  // ---- merge 8 wave partials; extract (dmin, idx); block-local outputs ----
  float contrib = 0.f, cnt = 0.f;
  if (tid < 256) {
    float bd = __uint_as_float(merged[0][tid]);
#pragma unroll
    for (int ww = 1; ww < 8; ++ww) bd = fminf(bd, __uint_as_float(merged[ww][tid]));
    u32 bits = __float_as_uint(bd);
    u32 bi = bits & 0x7FFu;                            // global q index
    float dmin = __uint_as_float(bits & 0xFFFFF800u);  // truncated min d'
    float pwv = pws[tid];                              // pn (+BIG if invalid p)
    bool valid = (pwv < 1e9f);
    contrib = valid ? (dmin + pwv) : 0.f;              // + ||p||^2, mask invalid
    cnt = valid ? 1.f : 0.f;
    if (valid) atomicOr(&hitlds[bi >> 5], 1u << (bi & 31));
  }
  for (int o = 32; o > 0; o >>= 1) {
    contrib += __shfl_down(contrib, o, 64);
    cnt += __shfl_down(cnt, o, 64);
  }
  if (tid < 256 && lane == 0) { redc[w] = contrib; redn[w] = cnt; }
  __syncthreads();
  if (tid == 0) {
    sums_part[bid] = redc[0] + redc[1] + redc[2] + redc[3];
    cnts_part[bid] = redn[0] + redn[1] + redn[2] + redn[3];
  }
  if (tid < 64) hitpart[bid * 64 + tid] = hitlds[tid];
}

// One block, 512 threads: 8 threads per (side,b); OR 8 pc-partials, popcount,
// sum part sums/cnts, then one wave assembles the 4 scalars.
__global__ __launch_bounds__(512) void assemble_kernel(const u32* __restrict__ hitpart,
                                                       const float* __restrict__ sums_part,
                                                       const float* __restrict__ cnts_part,
                                                       float* __restrict__ out) {
  __shared__ float hs[64], ss[64], cs[64];
  int tid = threadIdx.x;
  int sb = tid >> 3, c = tid & 7;  // sb = side*32+b; part bid = sb*8 + pc
  float h = 0.f;
  for (int wd = c; wd < 64; wd += 8) {
    u32 m = 0u;
#pragma unroll
    for (int blk = 0; blk < 8; ++blk) m |= hitpart[(sb * 8 + blk) * 64 + wd];
    h += (float)__popc(m);
  }
  h += __shfl_down(h, 4, 8);
  h += __shfl_down(h, 2, 8);
  h += __shfl_down(h, 1, 8);
  if (c == 0) {
    float s = 0.f, n = 0.f;
#pragma unroll
    for (int blk = 0; blk < 8; ++blk) {
      s += sums_part[sb * 8 + blk];
      n += cnts_part[sb * 8 + blk];
    }
    hs[sb] = h; ss[sb] = s; cs[sb] = n;
  }
  __syncthreads();
  if (tid < 64) {
    float cd = 0.f, cov = 0.f, qual = 0.f;
    if (tid < BB) {
      float nx = cs[tid], ny = cs[BB + tid];
      cd = ss[tid] / nx + ss[BB + tid] / ny;
      cov = hs[tid] / ny;        // side0 (p=x) hits y indices: /ny
      qual = hs[BB + tid] / nx;  // side1 (p=y) hits x indices: /nx
    }
    for (int o = 32; o > 0; o >>= 1) {
      cd += __shfl_down(cd, o, 64);
      cov += __shfl_down(cov, o, 64);
      qual += __shfl_down(qual, o, 64);
    }
    if (tid == 0) {
      cd /= (float)BB; cov /= (float)BB; qual /= (float)BB;
      out[0] = cd - 1e-4f * cov - 1e-4f * qual;  // WCD*cd - WCOV*cov - WQUAL*qual
      out[1] = cd;
      out[2] = cov;
      out[3] = qual;
    }
  }
}

extern "C" void kernel_launch(void* const* d_in, const int* in_sizes, int n_in,
                              void* d_out, int out_size, void* d_ws, size_t ws_size,
                              hipStream_t stream) {
  const float* x = (const float*)d_in[0];
  const float* y = (const float*)d_in[1];
  float* out = (float*)d_out;
  char* ws = (char*)d_ws;

  // ws layout (all regions fully written by producers; no memset needed):
  //   [0, 128KB)      hitpart: 512 blocks x 64 u32
  //   [128KB, +2KB)   sums_part: 512 f32
  //   [130KB, +2KB)   cnts_part: 512 f32
  u32* hitpart = (u32*)ws;
  float* sums_part = (float*)(ws + 131072);
  float* cnts_part = (float*)(ws + 133120);

  nn_fused_kernel<<<512, 512, 0, stream>>>(x, y, hitpart, sums_part, cnts_part);
  assemble_kernel<<<1, 512, 0, stream>>>(hitpart, sums_part, cnts_part, out);
}

// Round 11
// 90.886 us; speedup vs baseline: 1.1377x; 1.0156x over previous
//
#include <hip/hip_runtime.h>
#include <stdint.h>

// NormalizedLoss: batched chamfer + coverage/quality on point clouds.
// x: [32, 2048, 3] fp32, y: [32, 2048, 3] fp32 -> out: [val, cd, cov, qual] fp32.
//
// R11: R10 proved instruction mix is not the limiter (asm pk_fma changed
// nothing; true VALU busy ~12-13us of 40). The stall is LDS-read latency at
// only 4 waves/SIMD. Fix = TLP: split q 2-way ACROSS blocks -> grid 1024,
// LDS 24KB/block -> 4 blocks/CU = 32 waves/CU = 8 waves/SIMD
// (launch_bounds(512,8) caps VGPR at 64; body uses 52). nn emits per-p
// embedded (d|idx) u32 partials; merge_kernel combines the two q-halves,
// recomputes pn, scatters hits, reduces sums. 3 dispatches.

#define BB 32
#define NP 2048
#define BIGF 1e10f

typedef unsigned int u32;
typedef float f2 __attribute__((ext_vector_type(2)));

// embed 11-bit global q-index in the mantissa: float order ~ (d, idx) lex
#define EMB(d, jg) __uint_as_float((__float_as_uint(d) & 0xFFFFF800u) | (jg))

__device__ __forceinline__ f2 pk_fma(f2 a, f2 b, f2 c) {
  f2 d;
  asm("v_pk_fma_f32 %0, %1, %2, %3" : "=v"(d) : "v"(a), "v"(b), "v"(c));
  return d;
}
__device__ __forceinline__ float min3(float a, float b, float c) {
  float r;
  asm("v_min3_f32 %0, %1, %2, %3" : "=v"(r) : "v"(a), "v"(b), "v"(c));
  return r;
}

__global__ __launch_bounds__(512, 8) void nn_kernel(const float* __restrict__ x,
                                                    const float* __restrict__ y,
                                                    u32* __restrict__ part) {
  int bid = blockIdx.x;  // 1024 blocks: side(1)|b(5)|pc(3)|qc(1)
  int side = bid >> 9;
  int b = (bid >> 4) & 31;
  int pc = (bid >> 1) & 7;
  int qc = bid & 1;
  int tid = threadIdx.x;
  int w = __builtin_amdgcn_readfirstlane(tid >> 6);  // 0..7, wave-uniform
  int lane = tid & 63;

  __shared__ float4 qs[1024];     // 16KB; rec r -> qs[2r]=(x0,x1,y0,y1), qs[2r+1]=(z0,z1,n0,n1)
  __shared__ u32 merged[8][256];  // 8KB per-wave embedded (d|idx) partials

  // ---- stage this block's 1024 q (qc half); 2 points per thread ----
  {
    const float* qraw = (side ? x : y) + (b * NP + qc * 1024) * 3 + tid * 6;
    f2 a01 = *(const f2*)(qraw);      // x0,y0
    f2 a23 = *(const f2*)(qraw + 2);  // z0,x1
    f2 a45 = *(const f2*)(qraw + 4);  // y1,z1
    float q0x = a01.x, q0y = a01.y, q0z = a23.x;
    float q1x = a23.y, q1y = a45.x, q1z = a45.y;
    float n0 = q0x * q0x + q0y * q0y + q0z * q0z;
    float n1 = q1x * q1x + q1y * q1y + q1z * q1z;
    if (q0x + q0y + q0z == 0.f) n0 += BIGF;  // invalid rows out of every min
    if (q1x + q1y + q1z == 0.f) n1 += BIGF;
    qs[2 * tid]     = make_float4(q0x, q1x, q0y, q1y);
    qs[2 * tid + 1] = make_float4(q0z, q1z, n0, n1);
  }

  // ---- p prologue: every wave loads the SAME 256 p; -2p dup'd into f2 ----
  const float* praw = (side ? y : x) + (b * NP + pc * 256) * 3;
  f2 pmx[4], pmy[4], pmz[4];
  float best[4];
#pragma unroll
  for (int k = 0; k < 4; ++k) {
    int pl = lane + 64 * k;
    float p0 = praw[3 * pl], p1 = praw[3 * pl + 1], p2 = praw[3 * pl + 2];
    pmx[k] = (f2){-2.f * p0, -2.f * p0};
    pmy[k] = (f2){-2.f * p1, -2.f * p1};
    pmz[k] = (f2){-2.f * p2, -2.f * p2};
    best[k] = 3.0e38f;
  }
  __syncthreads();

  // ---- inner loop: wave's 64 records (128 q) vs its 4 p-points ----
  const float4* qr = &qs[w * 128];
  u32 je = (u32)(qc * 1024 + w * 128);  // global q index of this wave's rec 0
#pragma unroll 8
  for (int r = 0; r < 64; ++r) {
    float4 A = qr[2 * r];      // wave-uniform ds_read_b128 (broadcast)
    float4 B = qr[2 * r + 1];
    f2 qx2 = (f2){A.x, A.y};
    f2 qy2 = (f2){A.z, A.w};
    f2 qz2 = (f2){B.x, B.y};
    f2 qw2 = (f2){B.z, B.w};
    u32 jg = je + 2 * (u32)r, jg1 = jg + 1;
#pragma unroll
    for (int k = 0; k < 4; ++k) {
      f2 d2 = pk_fma(qx2, pmx[k], pk_fma(qy2, pmy[k], pk_fma(qz2, pmz[k], qw2)));
      best[k] = min3(best[k], EMB(d2.x, jg), EMB(d2.y, jg1));
    }
  }

  merged[w][lane +   0] = __float_as_uint(best[0]);
  merged[w][lane +  64] = __float_as_uint(best[1]);
  merged[w][lane + 128] = __float_as_uint(best[2]);
  merged[w][lane + 192] = __float_as_uint(best[3]);
  __syncthreads();

  // ---- merge 8 wave partials; store embedded u32 per p ----
  if (tid < 256) {
    float bd = __uint_as_float(merged[0][tid]);
#pragma unroll
    for (int ww = 1; ww < 8; ++ww) bd = fminf(bd, __uint_as_float(merged[ww][tid]));
    // part[qc][side*65536 + b*2048 + pc*256 + tid]
    part[qc * 131072 + side * 65536 + b * 2048 + pc * 256 + tid] = __float_as_uint(bd);
  }
}

// 512 blocks x 256 thr: combine qc halves, recompute pn/validity, scatter
// hits into a block-local bitmask, reduce sums/cnts per block.
__global__ __launch_bounds__(256) void merge_kernel(const float* __restrict__ x,
                                                    const float* __restrict__ y,
                                                    const u32* __restrict__ part,
                                                    u32* __restrict__ hitpart,
                                                    float* __restrict__ sums_part,
                                                    float* __restrict__ cnts_part) {
  int bid = blockIdx.x;  // 512: side(1)|b(5)|pc(3)  (same decomposition as assemble expects)
  int side = bid >> 8;
  int b = (bid >> 3) & 31;
  int pc = bid & 7;
  int tid = threadIdx.x;
  int lane = tid & 63, w = tid >> 6;

  __shared__ u32 hitlds[64];
  __shared__ float redc[4], redn[4];
  if (tid < 64) hitlds[tid] = 0u;
  __syncthreads();

  int pidx = side * 65536 + b * 2048 + pc * 256 + tid;
  float bd = fminf(__uint_as_float(part[pidx]), __uint_as_float(part[131072 + pidx]));
  u32 bits = __float_as_uint(bd);
  u32 bi = bits & 0x7FFu;                            // global q index
  float dmin = __uint_as_float(bits & 0xFFFFF800u);  // truncated min d'
  const float* praw = (side ? y : x) + (b * NP + pc * 256 + tid) * 3;
  float p0 = praw[0], p1 = praw[1], p2 = praw[2];
  bool valid = (p0 + p1 + p2) != 0.f;
  float contrib = valid ? (dmin + p0 * p0 + p1 * p1 + p2 * p2) : 0.f;
  float cnt = valid ? 1.f : 0.f;
  if (valid) atomicOr(&hitlds[bi >> 5], 1u << (bi & 31));

  for (int o = 32; o > 0; o >>= 1) {
    contrib += __shfl_down(contrib, o, 64);
    cnt += __shfl_down(cnt, o, 64);
  }
  if (lane == 0) { redc[w] = contrib; redn[w] = cnt; }
  __syncthreads();
  if (tid == 0) {
    sums_part[bid] = redc[0] + redc[1] + redc[2] + redc[3];
    cnts_part[bid] = redn[0] + redn[1] + redn[2] + redn[3];
  }
  if (tid < 64) hitpart[bid * 64 + tid] = hitlds[tid];
}

// One block, 512 threads: 8 threads per (side,b); OR 8 pc-partials, popcount,
// sum part sums/cnts, then one wave assembles the 4 scalars.
__global__ __launch_bounds__(512) void assemble_kernel(const u32* __restrict__ hitpart,
                                                       const float* __restrict__ sums_part,
                                                       const float* __restrict__ cnts_part,
                                                       float* __restrict__ out) {
  __shared__ float hs[64], ss[64], cs[64];
  int tid = threadIdx.x;
  int sb = tid >> 3, c = tid & 7;  // sb = side*32+b; part bid = sb*8 + pc
  float h = 0.f;
  for (int wd = c; wd < 64; wd += 8) {
    u32 m = 0u;
#pragma unroll
    for (int blk = 0; blk < 8; ++blk) m |= hitpart[(sb * 8 + blk) * 64 + wd];
    h += (float)__popc(m);
  }
  h += __shfl_down(h, 4, 8);
  h += __shfl_down(h, 2, 8);
  h += __shfl_down(h, 1, 8);
  if (c == 0) {
    float s = 0.f, n = 0.f;
#pragma unroll
    for (int blk = 0; blk < 8; ++blk) {
      s += sums_part[sb * 8 + blk];
      n += cnts_part[sb * 8 + blk];
    }
    hs[sb] = h; ss[sb] = s; cs[sb] = n;
  }
  __syncthreads();
  if (tid < 64) {
    float cd = 0.f, cov = 0.f, qual = 0.f;
    if (tid < BB) {
      float nx = cs[tid], ny = cs[BB + tid];
      cd = ss[tid] / nx + ss[BB + tid] / ny;
      cov = hs[tid] / ny;        // side0 (p=x) hits y indices: /ny
      qual = hs[BB + tid] / nx;  // side1 (p=y) hits x indices: /nx
    }
    for (int o = 32; o > 0; o >>= 1) {
      cd += __shfl_down(cd, o, 64);
      cov += __shfl_down(cov, o, 64);
      qual += __shfl_down(qual, o, 64);
    }
    if (tid == 0) {
      cd /= (float)BB; cov /= (float)BB; qual /= (float)BB;
      out[0] = cd - 1e-4f * cov - 1e-4f * qual;  // WCD*cd - WCOV*cov - WQUAL*qual
      out[1] = cd;
      out[2] = cov;
      out[3] = qual;
    }
  }
}

extern "C" void kernel_launch(void* const* d_in, const int* in_sizes, int n_in,
                              void* d_out, int out_size, void* d_ws, size_t ws_size,
                              hipStream_t stream) {
  const float* x = (const float*)d_in[0];
  const float* y = (const float*)d_in[1];
  float* out = (float*)d_out;
  char* ws = (char*)d_ws;

  // ws layout (all regions fully written by producers; no memset needed):
  //   [0, 128KB)        hitpart: 512 blocks x 64 u32
  //   [128KB, +2KB)     sums_part: 512 f32
  //   [130KB, +2KB)     cnts_part: 512 f32
  //   [132KB, +1MB)     part: 2 qc x 131072 u32 embedded (d|idx)
  u32* hitpart = (u32*)ws;
  float* sums_part = (float*)(ws + 131072);
  float* cnts_part = (float*)(ws + 133120);
  u32* part = (u32*)(ws + 135168);

  nn_kernel<<<1024, 512, 0, stream>>>(x, y, part);
  merge_kernel<<<512, 256, 0, stream>>>(x, y, part, hitpart, sums_part, cnts_part);
  assemble_kernel<<<1, 512, 0, stream>>>(hitpart, sums_part, cnts_part, out);
}